// Round 1
// baseline (21714.703 us; speedup 1.0000x reference)
//
#include <hip/hip_runtime.h>
#include <math.h>

#define BATCH 32
#define SEQT 384
#define DIM 768
#define D3 2304
#define NROWS (BATCH*SEQT)      // 12288
#define VTHRESH 0.95f

// ---------------- workspace layout (bytes) ----------------
#define OFF_XP   ((size_t)0)
#define SZ_XP    ((size_t)NROWS * D3 * 4)            // 113,246,208
#define OFF_ST   (OFF_XP + SZ_XP)
#define SZ_ST    ((size_t)NROWS * DIM * 4)           // 37,748,736
#define OFF_PR   (OFF_ST + SZ_ST)
#define SZ_PR    ((size_t)NROWS * 4)
#define OFF_WT   (OFF_PR + SZ_PR)
#define OFF_SS   (OFF_WT + SZ_PR)
#define OFF_SE   (OFF_SS + SZ_PR)
#define OFF_NS   (OFF_SE + SZ_PR)
#define OFF_FL   (OFF_NS + 256)

// =========================================================
// K1: xp[m][n] = sum_k emb[sent[m]][k] * w_ih[n][k] + b_ih[n]
// 128x128x16 tile, 256 threads, 8x8 microtile.
// =========================================================
__global__ __launch_bounds__(256, 2) void k_xp(
    const int* __restrict__ sent, const float* __restrict__ emb,
    const float* __restrict__ w_ih, const float* __restrict__ b_ih,
    float* __restrict__ xp)
{
    __shared__ float As[16][132];
    __shared__ float Bs[16][132];
    const int tid = threadIdx.x;
    const int mt = blockIdx.x, nt = blockIdx.y;
    const int tx = tid & 15, ty = tid >> 4;
    const int lm = tid >> 2;          // 0..63
    const int lk = (tid & 3) << 2;    // 0,4,8,12

    const long arow0 = (long)sent[mt*128 + lm] * DIM;
    const long arow1 = (long)sent[mt*128 + lm + 64] * DIM;
    const float* b0p = w_ih + (size_t)(nt*128 + lm) * DIM;
    const float* b1p = w_ih + (size_t)(nt*128 + lm + 64) * DIM;

    float acc[8][8];
    #pragma unroll
    for (int i = 0; i < 8; ++i)
        #pragma unroll
        for (int j = 0; j < 8; ++j) acc[i][j] = 0.f;

    for (int k0 = 0; k0 < DIM; k0 += 16) {
        float4 a0 = *(const float4*)(emb + arow0 + k0 + lk);
        float4 a1 = *(const float4*)(emb + arow1 + k0 + lk);
        float4 b0 = *(const float4*)(b0p + k0 + lk);
        float4 b1 = *(const float4*)(b1p + k0 + lk);
        __syncthreads();
        As[lk+0][lm] = a0.x; As[lk+1][lm] = a0.y; As[lk+2][lm] = a0.z; As[lk+3][lm] = a0.w;
        As[lk+0][lm+64] = a1.x; As[lk+1][lm+64] = a1.y; As[lk+2][lm+64] = a1.z; As[lk+3][lm+64] = a1.w;
        Bs[lk+0][lm] = b0.x; Bs[lk+1][lm] = b0.y; Bs[lk+2][lm] = b0.z; Bs[lk+3][lm] = b0.w;
        Bs[lk+0][lm+64] = b1.x; Bs[lk+1][lm+64] = b1.y; Bs[lk+2][lm+64] = b1.z; Bs[lk+3][lm+64] = b1.w;
        __syncthreads();
        #pragma unroll
        for (int k = 0; k < 16; ++k) {
            float4 av0 = *(const float4*)&As[k][ty*8];
            float4 av1 = *(const float4*)&As[k][ty*8+4];
            float4 bv0 = *(const float4*)&Bs[k][tx*8];
            float4 bv1 = *(const float4*)&Bs[k][tx*8+4];
            float a[8] = {av0.x,av0.y,av0.z,av0.w,av1.x,av1.y,av1.z,av1.w};
            float b[8] = {bv0.x,bv0.y,bv0.z,bv0.w,bv1.x,bv1.y,bv1.z,bv1.w};
            #pragma unroll
            for (int i = 0; i < 8; ++i)
                #pragma unroll
                for (int j = 0; j < 8; ++j)
                    acc[i][j] += a[i]*b[j];
        }
    }

    const int m0 = mt*128 + ty*8;
    const int n0 = nt*128 + tx*8;
    float4 bi0 = *(const float4*)(b_ih + n0);
    float4 bi1 = *(const float4*)(b_ih + n0 + 4);
    #pragma unroll
    for (int i = 0; i < 8; ++i) {
        float4 v0, v1;
        v0.x = acc[i][0] + bi0.x; v0.y = acc[i][1] + bi0.y;
        v0.z = acc[i][2] + bi0.z; v0.w = acc[i][3] + bi0.w;
        v1.x = acc[i][4] + bi1.x; v1.y = acc[i][5] + bi1.y;
        v1.z = acc[i][6] + bi1.z; v1.w = acc[i][7] + bi1.w;
        *(float4*)(xp + (size_t)(m0+i)*D3 + n0)     = v0;
        *(float4*)(xp + (size_t)(m0+i)*D3 + n0 + 4) = v1;
    }
}

// =========================================================
// K2: persistent GRU recurrence.
// 256 WGs x 384 threads. WG g: jb = g%128 (6 hidden dims), bg = g/128 (16 batches).
// w_hh slice (18 rows x 768) in LDS; per-step sync via per-WG flags.
// thread: q = tid&3 (K-quarter), p = tid>>2: bl = p&15, j = p>>4.
// =========================================================
#define JB 6
#define NBJ 128
#define BB 16
#define WROW 784   // 4 chunks of 196 (192 data + 4 pad) -> bank-conflict-free

__global__ __launch_bounds__(384, 1) void k_gru(
    const float* __restrict__ w_hh, const float* __restrict__ b_hh,
    const float* __restrict__ xp, float* states, int* flags)
{
    __shared__ float wl[18 * WROW];   // 56,448 B
    const int g  = blockIdx.x;
    const int jb = g & (NBJ - 1);
    const int bg = g >> 7;
    const int tid = threadIdx.x;

    // stage w_hh slice: rows gate*6+j for j in [jb*6, jb*6+6)
    for (int i = tid; i < 18 * DIM; i += 384) {
        int rr = i / DIM;
        int c  = i - rr * DIM;
        int gate = rr / JB, j = rr - gate * JB;
        wl[rr*WROW + (c/192)*196 + (c - (c/192)*192)] =
            w_hh[(size_t)(gate*DIM + jb*JB + j) * DIM + c];
    }

    const int q  = tid & 3;
    const int p  = tid >> 2;     // 0..95
    const int bl = p & 15;
    const int j  = p >> 4;       // 0..5
    const int b  = bg*BB + bl;
    const int jg = jb*JB + j;

    const float* wr = wl + (0*JB + j)*WROW + q*196;
    const float* wz = wl + (1*JB + j)*WROW + q*196;
    const float* wn = wl + (2*JB + j)*WROW + q*196;

    const float bhr = b_hh[jg];
    const float bhz = b_hh[DIM + jg];
    const float bhn = b_hh[2*DIM + jg];

    __syncthreads();

    for (int t = 0; t < SEQT; ++t) {
        if (t > 0) {
            if (tid < 64) {
                const int* f = flags + bg*NBJ;
                bool ok;
                do {
                    int v0 = __hip_atomic_load(f + tid,      __ATOMIC_ACQUIRE, __HIP_MEMORY_SCOPE_AGENT);
                    int v1 = __hip_atomic_load(f + 64 + tid, __ATOMIC_ACQUIRE, __HIP_MEMORY_SCOPE_AGENT);
                    ok = (v0 >= t) && (v1 >= t);
                } while (!__all(ok));
            }
            __syncthreads();
        }

        const float* xrow = xp + (size_t)(b*SEQT + t) * D3;
        float xr = xrow[jg], xz = xrow[DIM + jg], xn = xrow[2*DIM + jg];

        float ar = 0.f, az = 0.f, an = 0.f;
        float hold = 0.f;
        if (t > 0) {
            const float* hrow = states + (size_t)(b*SEQT + t - 1) * DIM;
            hold = hrow[jg];
            const float4* h4p = (const float4*)(hrow + q*192);
            const float4* r4p = (const float4*)wr;
            const float4* z4p = (const float4*)wz;
            const float4* n4p = (const float4*)wn;
            #pragma unroll 8
            for (int i = 0; i < 48; ++i) {
                float4 h4 = h4p[i];
                float4 r4 = r4p[i];
                float4 z4 = z4p[i];
                float4 n4 = n4p[i];
                ar += h4.x*r4.x + h4.y*r4.y + h4.z*r4.z + h4.w*r4.w;
                az += h4.x*z4.x + h4.y*z4.y + h4.z*z4.z + h4.w*z4.w;
                an += h4.x*n4.x + h4.y*n4.y + h4.z*n4.z + h4.w*n4.w;
            }
        }
        // butterfly reduce across the K-quad (lanes q=0..3 share full sums)
        ar += __shfl_xor(ar, 1); ar += __shfl_xor(ar, 2);
        az += __shfl_xor(az, 1); az += __shfl_xor(az, 2);
        an += __shfl_xor(an, 1); an += __shfl_xor(an, 2);

        float rg = 1.f / (1.f + expf(-(xr + ar + bhr)));
        float zg = 1.f / (1.f + expf(-(xz + az + bhz)));
        float ng = tanhf(xn + rg * (an + bhn));
        float hnew = (1.f - zg) * ng + zg * hold;

        if (q == 0) states[(size_t)(b*SEQT + t)*DIM + jg] = hnew;

        __threadfence();
        __syncthreads();
        if (tid == 0)
            __hip_atomic_store(flags + bg*NBJ + jb, t + 1,
                               __ATOMIC_RELEASE, __HIP_MEMORY_SCOPE_AGENT);
    }
}

// =========================================================
// K3: probs[r] = sigmoid(dot(states[r], w_act) + b_act)
// =========================================================
__global__ __launch_bounds__(256, 4) void k_probs(
    const float* __restrict__ states, const float* __restrict__ w_act,
    const float* __restrict__ b_act, float* __restrict__ probs,
    float* __restrict__ out_probs)
{
    int row  = blockIdx.x*4 + (threadIdx.x >> 6);
    int lane = threadIdx.x & 63;
    const float* sr = states + (size_t)row * DIM;
    float s = 0.f;
    #pragma unroll
    for (int i = 0; i < 3; ++i) {
        float4 v = *(const float4*)(sr + i*256 + lane*4);
        float4 w = *(const float4*)(w_act + i*256 + lane*4);
        s += v.x*w.x + v.y*w.y + v.z*w.z + v.w*w.w;
    }
    #pragma unroll
    for (int off = 32; off > 0; off >>= 1) s += __shfl_xor(s, off);
    if (lane == 0) {
        float pv = 1.f / (1.f + expf(-(s + b_act[0])));
        probs[row]     = pv;
        out_probs[row] = pv;
    }
}

// =========================================================
// K4: per-batch halting scan -> weights, segment bounds, n_segs
// =========================================================
__global__ void k_scan(const float* __restrict__ probs, float* __restrict__ weights,
                       int* __restrict__ seg_start, int* __restrict__ seg_end,
                       int* __restrict__ n_segs)
{
    int b = threadIdx.x;
    if (b >= BATCH) return;
    float acc = 0.f;
    int s = 0, start = 0;
    for (int t0 = 0; t0 < SEQT; t0 += 4) {
        float4 p4 = *(const float4*)(probs + b*SEQT + t0);
        float pv[4] = {p4.x, p4.y, p4.z, p4.w};
        #pragma unroll
        for (int k = 0; k < 4; ++k) {
            int t = t0 + k;
            float pp = pv[k];
            acc += pp;
            float w = pp;
            if (acc > VTHRESH) {
                w = pp - (acc - 1.0f);
                seg_start[b*SEQT + s] = start;
                seg_end[b*SEQT + s]   = t;
                s++; start = t + 1; acc = 0.f;
            }
            weights[b*SEQT + t] = w;
        }
    }
    n_segs[b] = s;
}

// =========================================================
// K5: embs row (b,s) = sum_{t in segment s} weights[b,t]*states[b,t,:]
//     invalid rows (s >= n_segs[b]) -> zeros. Writes all of out[0..B*T*D).
// =========================================================
__global__ __launch_bounds__(256, 4) void k_embs(
    const float* __restrict__ states, const float* __restrict__ weights,
    const int* __restrict__ seg_start, const int* __restrict__ seg_end,
    const int* __restrict__ n_segs, float* __restrict__ out)
{
    int r = blockIdx.x;
    int b = r / SEQT;
    int s = r - b*SEQT;
    int tid = threadIdx.x;
    float a0 = 0.f, a1 = 0.f, a2 = 0.f;
    if (s < n_segs[b]) {
        int st = seg_start[r], en = seg_end[r];
        for (int t = st; t <= en; ++t) {
            float w = weights[b*SEQT + t];
            const float* sp = states + (size_t)(b*SEQT + t) * DIM;
            a0 += w * sp[tid];
            a1 += w * sp[tid + 256];
            a2 += w * sp[tid + 512];
        }
    }
    float* o = out + (size_t)r * DIM;
    o[tid]       = a0;
    o[tid + 256] = a1;
    o[tid + 512] = a2;
}

__global__ void k_init(int* flags) { flags[threadIdx.x] = 0; }

extern "C" void kernel_launch(void* const* d_in, const int* in_sizes, int n_in,
                              void* d_out, int out_size, void* d_ws, size_t ws_size,
                              hipStream_t stream)
{
    const int*   sent  = (const int*)d_in[0];
    const float* emb   = (const float*)d_in[1];
    const float* w_ih  = (const float*)d_in[2];
    const float* w_hh  = (const float*)d_in[3];
    const float* b_ih  = (const float*)d_in[4];
    const float* b_hh  = (const float*)d_in[5];
    const float* w_act = (const float*)d_in[6];
    const float* b_act = (const float*)d_in[7];
    float* out = (float*)d_out;

    char* ws = (char*)d_ws;
    float* xp      = (float*)(ws + OFF_XP);
    float* states  = (float*)(ws + OFF_ST);
    float* probs   = (float*)(ws + OFF_PR);
    float* weights = (float*)(ws + OFF_WT);
    int*   sstart  = (int*)(ws + OFF_SS);
    int*   send    = (int*)(ws + OFF_SE);
    int*   nsegs   = (int*)(ws + OFF_NS);
    int*   flags   = (int*)(ws + OFF_FL);

    k_init<<<1, 256, 0, stream>>>(flags);
    k_xp<<<dim3(96, 18), 256, 0, stream>>>(sent, emb, w_ih, b_ih, xp);
    k_gru<<<256, 384, 0, stream>>>(w_hh, b_hh, xp, states, flags);
    k_probs<<<NROWS/4, 256, 0, stream>>>(states, w_act, b_act, probs,
                                         out + (size_t)NROWS * DIM);
    k_scan<<<1, 64, 0, stream>>>(probs, weights, sstart, send, nsegs);
    k_embs<<<NROWS, 256, 0, stream>>>(states, weights, sstart, send, nsegs, out);
}

// Round 2
// 4913.761 us; speedup vs baseline: 4.4192x; 4.4192x over previous
//
#include <hip/hip_runtime.h>
#include <math.h>

#define BATCH 32
#define SEQT 384
#define DIM 768
#define D3 2304
#define NROWS (BATCH*SEQT)      // 12288
#define VTHRESH 0.95f

// ---------------- workspace layout (bytes) ----------------
#define OFF_XP   ((size_t)0)
#define SZ_XP    ((size_t)NROWS * D3 * 4)            // 113,246,208
#define OFF_ST   (OFF_XP + SZ_XP)
#define SZ_ST    ((size_t)NROWS * DIM * 4)           // 37,748,736
#define OFF_PR   (OFF_ST + SZ_ST)
#define SZ_PR    ((size_t)NROWS * 4)
#define OFF_WT   (OFF_PR + SZ_PR)
#define OFF_SS   (OFF_WT + SZ_PR)
#define OFF_SE   (OFF_SS + SZ_PR)
#define OFF_NS   (OFF_SE + SZ_PR)
#define OFF_FL   (OFF_NS + 256)

#define DOT4(a,b) ((a).x*(b).x + (a).y*(b).y + (a).z*(b).z + (a).w*(b).w)

// =========================================================
// K1: xp[m][n] = sum_k emb[sent[m]][k] * w_ih[n][k] + b_ih[n]
// =========================================================
__global__ __launch_bounds__(256, 2) void k_xp(
    const int* __restrict__ sent, const float* __restrict__ emb,
    const float* __restrict__ w_ih, const float* __restrict__ b_ih,
    float* __restrict__ xp)
{
    __shared__ float As[16][132];
    __shared__ float Bs[16][132];
    const int tid = threadIdx.x;
    const int mt = blockIdx.x, nt = blockIdx.y;
    const int tx = tid & 15, ty = tid >> 4;
    const int lm = tid >> 2;          // 0..63
    const int lk = (tid & 3) << 2;    // 0,4,8,12

    const long arow0 = (long)sent[mt*128 + lm] * DIM;
    const long arow1 = (long)sent[mt*128 + lm + 64] * DIM;
    const float* b0p = w_ih + (size_t)(nt*128 + lm) * DIM;
    const float* b1p = w_ih + (size_t)(nt*128 + lm + 64) * DIM;

    float acc[8][8];
    #pragma unroll
    for (int i = 0; i < 8; ++i)
        #pragma unroll
        for (int j = 0; j < 8; ++j) acc[i][j] = 0.f;

    for (int k0 = 0; k0 < DIM; k0 += 16) {
        float4 a0 = *(const float4*)(emb + arow0 + k0 + lk);
        float4 a1 = *(const float4*)(emb + arow1 + k0 + lk);
        float4 b0 = *(const float4*)(b0p + k0 + lk);
        float4 b1 = *(const float4*)(b1p + k0 + lk);
        __syncthreads();
        As[lk+0][lm] = a0.x; As[lk+1][lm] = a0.y; As[lk+2][lm] = a0.z; As[lk+3][lm] = a0.w;
        As[lk+0][lm+64] = a1.x; As[lk+1][lm+64] = a1.y; As[lk+2][lm+64] = a1.z; As[lk+3][lm+64] = a1.w;
        Bs[lk+0][lm] = b0.x; Bs[lk+1][lm] = b0.y; Bs[lk+2][lm] = b0.z; Bs[lk+3][lm] = b0.w;
        Bs[lk+0][lm+64] = b1.x; Bs[lk+1][lm+64] = b1.y; Bs[lk+2][lm+64] = b1.z; Bs[lk+3][lm+64] = b1.w;
        __syncthreads();
        #pragma unroll
        for (int k = 0; k < 16; ++k) {
            float4 av0 = *(const float4*)&As[k][ty*8];
            float4 av1 = *(const float4*)&As[k][ty*8+4];
            float4 bv0 = *(const float4*)&Bs[k][tx*8];
            float4 bv1 = *(const float4*)&Bs[k][tx*8+4];
            float a[8] = {av0.x,av0.y,av0.z,av0.w,av1.x,av1.y,av1.z,av1.w};
            float b[8] = {bv0.x,bv0.y,bv0.z,bv0.w,bv1.x,bv1.y,bv1.z,bv1.w};
            #pragma unroll
            for (int i = 0; i < 8; ++i)
                #pragma unroll
                for (int j = 0; j < 8; ++j)
                    acc[i][j] += a[i]*b[j];
        }
    }

    const int m0 = mt*128 + ty*8;
    const int n0 = nt*128 + tx*8;
    float4 bi0 = *(const float4*)(b_ih + n0);
    float4 bi1 = *(const float4*)(b_ih + n0 + 4);
    #pragma unroll
    for (int i = 0; i < 8; ++i) {
        float4 v0, v1;
        v0.x = acc[i][0] + bi0.x; v0.y = acc[i][1] + bi0.y;
        v0.z = acc[i][2] + bi0.z; v0.w = acc[i][3] + bi0.w;
        v1.x = acc[i][4] + bi1.x; v1.y = acc[i][5] + bi1.y;
        v1.z = acc[i][6] + bi1.z; v1.w = acc[i][7] + bi1.w;
        *(float4*)(xp + (size_t)(m0+i)*D3 + n0)     = v0;
        *(float4*)(xp + (size_t)(m0+i)*D3 + n0 + 4) = v1;
    }
}

// =========================================================
// K2: persistent GRU recurrence, v2.
//   - NO acquire/release fences (they lower to buffer_inv / buffer_wbl2
//     on gfx950 and cost ~55us/step). All cross-WG exchange uses RELAXED
//     agent-scope atomics (plain bypass loads/stores to MALL).
//   - 256 WGs x 384 threads: jb = blockIdx%128 (6 hidden dims),
//     bg = blockIdx/128 (16 batches). Wave = j (dim within block).
//   - w_hh slice in REGISTERS (18 float4/thread); LDS stages h_{t-1}
//     (16x768 = 49KB) loaded cooperatively via bypass ULL loads.
//   - lane = c(0..31 K-split) + 32*bh(batch half). Reduce-scatter over c
//     leaves lane with gate sums for batch (c>>2)&7 of its half.
// =========================================================
#define HPAD 776   // 768 + 8 floats row pitch in LDS

__global__ __launch_bounds__(384, 1) void k_gru(
    const float* __restrict__ w_hh, const float* __restrict__ b_hh,
    const float* __restrict__ xp, float* states, int* flags)
{
    __shared__ float h_lds[16 * HPAD];   // 49,664 B

    const int tid = threadIdx.x;
    const int blk = blockIdx.x;
    const int jb  = blk & 127;
    const int bg  = blk >> 7;
    const int j    = tid >> 6;         // wave index 0..5
    const int lane = tid & 63;
    const int c    = lane & 31;
    const int bh   = lane >> 5;
    const int jg   = jb*6 + j;
    const int bloc  = (c >> 2) & 7;
    const int batch = bg*16 + bh*8 + bloc;
    const bool leader = ((c & 3) == 0);

    // staging assignment: 24 threads per batch row, each 16 ULLs (32 floats)
    const int srow = tid / 24;        // 0..15
    const int sir  = tid - srow*24;   // 0..23

    // w_hh slice into registers: rows gate*768 + jg, cols [c*24, c*24+24)
    float4 w4[3][6];
    #pragma unroll
    for (int g3 = 0; g3 < 3; ++g3) {
        const float* wr = w_hh + (size_t)(g3*DIM + jg)*DIM + c*24;
        #pragma unroll
        for (int kk = 0; kk < 6; ++kk) w4[g3][kk] = *(const float4*)(wr + kk*4);
    }
    const float bhr = b_hh[jg];
    const float bhz = b_hh[DIM + jg];
    const float bhn = b_hh[2*DIM + jg];

    float hold = 0.f;

    const unsigned long long* st_u = (const unsigned long long*)states;
    unsigned long long* hl_u = (unsigned long long*)h_lds;
    const size_t srow_base = ((size_t)(bg*16 + srow)*SEQT) * (DIM/2) + sir;
    const int    ldst_base = srow*(HPAD/2) + sir;

    for (int t = 0; t < SEQT; ++t) {
        // xp prefetch (independent of flags) — issue before the spin
        const float* xrow = xp + ((size_t)batch*SEQT + t)*D3 + jg;
        float xr = xrow[0], xz = xrow[DIM], xn = xrow[2*DIM];

        float ar = 0.f, az = 0.f, an = 0.f;
        if (t > 0) {
            // ---- wait for all 128 dim-WGs of this batch group at step t-1
            if (tid < 128) {
                const int* f = flags + bg*128 + tid;
                while (__hip_atomic_load(f, __ATOMIC_RELAXED,
                                         __HIP_MEMORY_SCOPE_AGENT) < t) {
                    __builtin_amdgcn_s_sleep(1);
                }
            }
            __syncthreads();
            asm volatile("" ::: "memory");

            // ---- Phase A: stage h_{t-1} (16 x 768) into LDS via bypass loads
            const unsigned long long* src = st_u + srow_base + (size_t)(t-1)*(DIM/2);
            #pragma unroll
            for (int k = 0; k < 16; ++k)
                hl_u[ldst_base + 24*k] =
                    __hip_atomic_load(src + 24*k, __ATOMIC_RELAXED,
                                      __HIP_MEMORY_SCOPE_AGENT);
            __syncthreads();

            // ---- Phase B: partial dots for 8 batches x 3 gates on K-slice c
            float v[24];
            #pragma unroll
            for (int i = 0; i < 24; ++i) v[i] = 0.f;
            const float* hb = h_lds + (bh*8)*HPAD + c*24;
            #pragma unroll
            for (int bb = 0; bb < 8; ++bb) {
                const float4* hp = (const float4*)(hb + bb*HPAD);
                #pragma unroll
                for (int kk = 0; kk < 6; ++kk) {
                    float4 h4 = hp[kk];
                    v[bb*3+0] += DOT4(h4, w4[0][kk]);
                    v[bb*3+1] += DOT4(h4, w4[1][kk]);
                    v[bb*3+2] += DOT4(h4, w4[2][kk]);
                }
            }
            // ---- reduce-scatter over the 32 c-lanes (bits 4,3,2 -> batch)
            #pragma unroll
            for (int i = 0; i < 12; ++i) {
                float send = (c & 16) ? v[i] : v[i+12];
                float keep = (c & 16) ? v[i+12] : v[i];
                v[i] = keep + __shfl_xor(send, 16);
            }
            #pragma unroll
            for (int i = 0; i < 6; ++i) {
                float send = (c & 8) ? v[i] : v[i+6];
                float keep = (c & 8) ? v[i+6] : v[i];
                v[i] = keep + __shfl_xor(send, 8);
            }
            #pragma unroll
            for (int i = 0; i < 3; ++i) {
                float send = (c & 4) ? v[i] : v[i+3];
                float keep = (c & 4) ? v[i+3] : v[i];
                v[i] = keep + __shfl_xor(send, 4);
            }
            #pragma unroll
            for (int i = 0; i < 3; ++i) v[i] += __shfl_xor(v[i], 2);
            #pragma unroll
            for (int i = 0; i < 3; ++i) v[i] += __shfl_xor(v[i], 1);
            ar = v[0]; az = v[1]; an = v[2];
        }

        float rg = 1.f / (1.f + expf(-(xr + ar + bhr)));
        float zg = 1.f / (1.f + expf(-(xz + az + bhz)));
        float ng = tanhf(xn + rg * (an + bhn));
        float hnew = (1.f - zg) * ng + zg * hold;
        hold = hnew;

        if (leader)
            __hip_atomic_store(states + (size_t)(batch*SEQT + t)*DIM + jg, hnew,
                               __ATOMIC_RELAXED, __HIP_MEMORY_SCOPE_AGENT);
        // drain bypass stores (they complete at the coherence point), then flag
        asm volatile("s_waitcnt vmcnt(0)" ::: "memory");
        __syncthreads();
        if (tid == 0)
            __hip_atomic_store(flags + bg*128 + jb, t + 1,
                               __ATOMIC_RELAXED, __HIP_MEMORY_SCOPE_AGENT);
    }
}

// =========================================================
// K3: probs[r] = sigmoid(dot(states[r], w_act) + b_act)
// =========================================================
__global__ __launch_bounds__(256, 4) void k_probs(
    const float* __restrict__ states, const float* __restrict__ w_act,
    const float* __restrict__ b_act, float* __restrict__ probs,
    float* __restrict__ out_probs)
{
    int row  = blockIdx.x*4 + (threadIdx.x >> 6);
    int lane = threadIdx.x & 63;
    const float* sr = states + (size_t)row * DIM;
    float s = 0.f;
    #pragma unroll
    for (int i = 0; i < 3; ++i) {
        float4 v = *(const float4*)(sr + i*256 + lane*4);
        float4 w = *(const float4*)(w_act + i*256 + lane*4);
        s += v.x*w.x + v.y*w.y + v.z*w.z + v.w*w.w;
    }
    #pragma unroll
    for (int off = 32; off > 0; off >>= 1) s += __shfl_xor(s, off);
    if (lane == 0) {
        float pv = 1.f / (1.f + expf(-(s + b_act[0])));
        probs[row]     = pv;
        out_probs[row] = pv;
    }
}

// =========================================================
// K4: per-batch halting scan -> weights, segment bounds, n_segs
// =========================================================
__global__ void k_scan(const float* __restrict__ probs, float* __restrict__ weights,
                       int* __restrict__ seg_start, int* __restrict__ seg_end,
                       int* __restrict__ n_segs)
{
    int b = threadIdx.x;
    if (b >= BATCH) return;
    float acc = 0.f;
    int s = 0, start = 0;
    for (int t0 = 0; t0 < SEQT; t0 += 4) {
        float4 p4 = *(const float4*)(probs + b*SEQT + t0);
        float pv[4] = {p4.x, p4.y, p4.z, p4.w};
        #pragma unroll
        for (int k = 0; k < 4; ++k) {
            int t = t0 + k;
            float pp = pv[k];
            acc += pp;
            float w = pp;
            if (acc > VTHRESH) {
                w = pp - (acc - 1.0f);
                seg_start[b*SEQT + s] = start;
                seg_end[b*SEQT + s]   = t;
                s++; start = t + 1; acc = 0.f;
            }
            weights[b*SEQT + t] = w;
        }
    }
    n_segs[b] = s;
}

// =========================================================
// K5: embs row (b,s) = sum_{t in segment s} weights[b,t]*states[b,t,:]
// =========================================================
__global__ __launch_bounds__(256, 4) void k_embs(
    const float* __restrict__ states, const float* __restrict__ weights,
    const int* __restrict__ seg_start, const int* __restrict__ seg_end,
    const int* __restrict__ n_segs, float* __restrict__ out)
{
    int r = blockIdx.x;
    int b = r / SEQT;
    int s = r - b*SEQT;
    int tid = threadIdx.x;
    float a0 = 0.f, a1 = 0.f, a2 = 0.f;
    if (s < n_segs[b]) {
        int st = seg_start[r], en = seg_end[r];
        for (int t = st; t <= en; ++t) {
            float w = weights[b*SEQT + t];
            const float* sp = states + (size_t)(b*SEQT + t) * DIM;
            a0 += w * sp[tid];
            a1 += w * sp[tid + 256];
            a2 += w * sp[tid + 512];
        }
    }
    float* o = out + (size_t)r * DIM;
    o[tid]       = a0;
    o[tid + 256] = a1;
    o[tid + 512] = a2;
}

__global__ void k_init(int* flags) { flags[threadIdx.x] = 0; }

extern "C" void kernel_launch(void* const* d_in, const int* in_sizes, int n_in,
                              void* d_out, int out_size, void* d_ws, size_t ws_size,
                              hipStream_t stream)
{
    const int*   sent  = (const int*)d_in[0];
    const float* emb   = (const float*)d_in[1];
    const float* w_ih  = (const float*)d_in[2];
    const float* w_hh  = (const float*)d_in[3];
    const float* b_ih  = (const float*)d_in[4];
    const float* b_hh  = (const float*)d_in[5];
    const float* w_act = (const float*)d_in[6];
    const float* b_act = (const float*)d_in[7];
    float* out = (float*)d_out;

    char* ws = (char*)d_ws;
    float* xp      = (float*)(ws + OFF_XP);
    float* states  = (float*)(ws + OFF_ST);
    float* probs   = (float*)(ws + OFF_PR);
    float* weights = (float*)(ws + OFF_WT);
    int*   sstart  = (int*)(ws + OFF_SS);
    int*   send    = (int*)(ws + OFF_SE);
    int*   nsegs   = (int*)(ws + OFF_NS);
    int*   flags   = (int*)(ws + OFF_FL);

    k_init<<<1, 256, 0, stream>>>(flags);
    k_xp<<<dim3(96, 18), 256, 0, stream>>>(sent, emb, w_ih, b_ih, xp);
    k_gru<<<256, 384, 0, stream>>>(w_hh, b_hh, xp, states, flags);
    k_probs<<<NROWS/4, 256, 0, stream>>>(states, w_act, b_act, probs,
                                         out + (size_t)NROWS * DIM);
    k_scan<<<1, 64, 0, stream>>>(probs, weights, sstart, send, nsegs);
    k_embs<<<NROWS, 256, 0, stream>>>(states, weights, sstart, send, nsegs, out);
}

// Round 3
// 4711.542 us; speedup vs baseline: 4.6088x; 1.0429x over previous
//
#include <hip/hip_runtime.h>
#include <math.h>

#define BATCH 32
#define SEQT 384
#define DIM 768
#define D3 2304
#define NROWS (BATCH*SEQT)      // 12288
#define VTHRESH 0.95f

// ---------------- workspace layout (bytes) ----------------
#define OFF_XP   ((size_t)0)
#define SZ_XP    ((size_t)NROWS * D3 * 4)            // 113,246,208
#define OFF_ST   (OFF_XP + SZ_XP)
#define SZ_ST    ((size_t)NROWS * DIM * 4)           // 37,748,736
#define OFF_PR   (OFF_ST + SZ_ST)
#define SZ_PR    ((size_t)NROWS * 4)
#define OFF_WT   (OFF_PR + SZ_PR)
#define OFF_SS   (OFF_WT + SZ_PR)
#define OFF_SE   (OFF_SS + SZ_PR)
#define OFF_NS   (OFF_SE + SZ_PR)
#define OFF_CNT  (OFF_NS + 256)
// counters: 2 bg x 384 t, each padded to 64B (16 ints) = 49,152 B
#define NCNT     (2 * SEQT * 16)

#define DOT4(a,b) ((a).x*(b).x + (a).y*(b).y + (a).z*(b).z + (a).w*(b).w)

// =========================================================
// K1: xp[m][n] = sum_k emb[sent[m]][k] * w_ih[n][k] + b_ih[n]
// =========================================================
__global__ __launch_bounds__(256, 2) void k_xp(
    const int* __restrict__ sent, const float* __restrict__ emb,
    const float* __restrict__ w_ih, const float* __restrict__ b_ih,
    float* __restrict__ xp)
{
    __shared__ float As[16][132];
    __shared__ float Bs[16][132];
    const int tid = threadIdx.x;
    const int mt = blockIdx.x, nt = blockIdx.y;
    const int tx = tid & 15, ty = tid >> 4;
    const int lm = tid >> 2;          // 0..63
    const int lk = (tid & 3) << 2;    // 0,4,8,12

    const long arow0 = (long)sent[mt*128 + lm] * DIM;
    const long arow1 = (long)sent[mt*128 + lm + 64] * DIM;
    const float* b0p = w_ih + (size_t)(nt*128 + lm) * DIM;
    const float* b1p = w_ih + (size_t)(nt*128 + lm + 64) * DIM;

    float acc[8][8];
    #pragma unroll
    for (int i = 0; i < 8; ++i)
        #pragma unroll
        for (int j = 0; j < 8; ++j) acc[i][j] = 0.f;

    for (int k0 = 0; k0 < DIM; k0 += 16) {
        float4 a0 = *(const float4*)(emb + arow0 + k0 + lk);
        float4 a1 = *(const float4*)(emb + arow1 + k0 + lk);
        float4 b0 = *(const float4*)(b0p + k0 + lk);
        float4 b1 = *(const float4*)(b1p + k0 + lk);
        __syncthreads();
        As[lk+0][lm] = a0.x; As[lk+1][lm] = a0.y; As[lk+2][lm] = a0.z; As[lk+3][lm] = a0.w;
        As[lk+0][lm+64] = a1.x; As[lk+1][lm+64] = a1.y; As[lk+2][lm+64] = a1.z; As[lk+3][lm+64] = a1.w;
        Bs[lk+0][lm] = b0.x; Bs[lk+1][lm] = b0.y; Bs[lk+2][lm] = b0.z; Bs[lk+3][lm] = b0.w;
        Bs[lk+0][lm+64] = b1.x; Bs[lk+1][lm+64] = b1.y; Bs[lk+2][lm+64] = b1.z; Bs[lk+3][lm+64] = b1.w;
        __syncthreads();
        #pragma unroll
        for (int k = 0; k < 16; ++k) {
            float4 av0 = *(const float4*)&As[k][ty*8];
            float4 av1 = *(const float4*)&As[k][ty*8+4];
            float4 bv0 = *(const float4*)&Bs[k][tx*8];
            float4 bv1 = *(const float4*)&Bs[k][tx*8+4];
            float a[8] = {av0.x,av0.y,av0.z,av0.w,av1.x,av1.y,av1.z,av1.w};
            float b[8] = {bv0.x,bv0.y,bv0.z,bv0.w,bv1.x,bv1.y,bv1.z,bv1.w};
            #pragma unroll
            for (int i = 0; i < 8; ++i)
                #pragma unroll
                for (int j = 0; j < 8; ++j)
                    acc[i][j] += a[i]*b[j];
        }
    }

    const int m0 = mt*128 + ty*8;
    const int n0 = nt*128 + tx*8;
    float4 bi0 = *(const float4*)(b_ih + n0);
    float4 bi1 = *(const float4*)(b_ih + n0 + 4);
    #pragma unroll
    for (int i = 0; i < 8; ++i) {
        float4 v0, v1;
        v0.x = acc[i][0] + bi0.x; v0.y = acc[i][1] + bi0.y;
        v0.z = acc[i][2] + bi0.z; v0.w = acc[i][3] + bi0.w;
        v1.x = acc[i][4] + bi1.x; v1.y = acc[i][5] + bi1.y;
        v1.z = acc[i][6] + bi1.z; v1.w = acc[i][7] + bi1.w;
        *(float4*)(xp + (size_t)(m0+i)*D3 + n0)     = v0;
        *(float4*)(xp + (size_t)(m0+i)*D3 + n0 + 4) = v1;
    }
}

// =========================================================
// K2: persistent GRU recurrence, v3.
//   - Barrier: per-(bg,t) arrival counter on its own 64B line.
//     Producers: one fire-and-forget relaxed agent atomic_add per WG.
//     Consumers: ONE polling lane per wave (6 loads/WG/round), vs the
//     v2 poll-storm of 128 lanes x 128 packed flags (30 G loads/s on
//     8 MALL lines -> self-jamming the coherence point).
//   - Phase B LDS reads remapped: lane c's K-slice = cols {kk*128+c*4},
//     canonical stride-16B ds_read_b128, conflict-free (v2: stride 96B,
//     1.26e8 conflict cycles).
// =========================================================
#define HPAD 776   // 768 + 8 floats row pitch in LDS

__global__ __launch_bounds__(384, 1) void k_gru(
    const float* __restrict__ w_hh, const float* __restrict__ b_hh,
    const float* __restrict__ xp, float* states, int* cnt)
{
    __shared__ float h_lds[16 * HPAD];   // 49,664 B

    const int tid = threadIdx.x;
    const int blk = blockIdx.x;
    const int jb  = blk & 127;
    const int bg  = blk >> 7;
    const int j    = tid >> 6;         // wave index 0..5
    const int lane = tid & 63;
    const int c    = lane & 31;
    const int bh   = lane >> 5;
    const int jg   = jb*6 + j;
    const int bloc  = (c >> 2) & 7;
    const int batch = bg*16 + bh*8 + bloc;
    const bool leader = ((c & 3) == 0);

    // staging assignment: 24 threads per batch row, each 16 ULLs (32 floats)
    const int srow = tid / 24;        // 0..15
    const int sir  = tid - srow*24;   // 0..23

    // w_hh slice into registers: rows gate*768 + jg, cols {kk*128 + c*4 .. +3}
    float4 w4[3][6];
    #pragma unroll
    for (int g3 = 0; g3 < 3; ++g3) {
        const float* wr = w_hh + (size_t)(g3*DIM + jg)*DIM + c*4;
        #pragma unroll
        for (int kk = 0; kk < 6; ++kk) w4[g3][kk] = *(const float4*)(wr + kk*128);
    }
    const float bhr = b_hh[jg];
    const float bhz = b_hh[DIM + jg];
    const float bhn = b_hh[2*DIM + jg];

    float hold = 0.f;

    const unsigned long long* st_u = (const unsigned long long*)states;
    unsigned long long* hl_u = (unsigned long long*)h_lds;
    const size_t srow_base = ((size_t)(bg*16 + srow)*SEQT) * (DIM/2) + sir;
    const int    ldst_base = srow*(HPAD/2) + sir;

    for (int t = 0; t < SEQT; ++t) {
        // xp prefetch (independent of barrier) — issue before the spin
        const float* xrow = xp + ((size_t)batch*SEQT + t)*D3 + jg;
        float xr = xrow[0], xz = xrow[DIM], xn = xrow[2*DIM];

        float ar = 0.f, az = 0.f, an = 0.f;
        if (t > 0) {
            // ---- wait for all 128 dim-WGs of this bg to post step t-1
            if (lane == 0) {
                const int* cp = cnt + (bg*SEQT + (t-1))*16;
                while (__hip_atomic_load(cp, __ATOMIC_RELAXED,
                                         __HIP_MEMORY_SCOPE_AGENT) < 128) {
                    __builtin_amdgcn_s_sleep(1);
                }
            }
            __syncthreads();
            asm volatile("" ::: "memory");

            // ---- Phase A: stage h_{t-1} (16 x 768) into LDS via bypass loads
            const unsigned long long* src = st_u + srow_base + (size_t)(t-1)*(DIM/2);
            #pragma unroll
            for (int k = 0; k < 16; ++k)
                hl_u[ldst_base + 24*k] =
                    __hip_atomic_load(src + 24*k, __ATOMIC_RELAXED,
                                      __HIP_MEMORY_SCOPE_AGENT);
            __syncthreads();

            // ---- Phase B: partial dots for 8 batches x 3 gates on K-slice c
            float v[24];
            #pragma unroll
            for (int i = 0; i < 24; ++i) v[i] = 0.f;
            const float* hb = h_lds + (bh*8)*HPAD + c*4;
            #pragma unroll
            for (int bb = 0; bb < 8; ++bb) {
                const float* hr = hb + bb*HPAD;
                #pragma unroll
                for (int kk = 0; kk < 6; ++kk) {
                    float4 h4 = *(const float4*)(hr + kk*128);
                    v[bb*3+0] += DOT4(h4, w4[0][kk]);
                    v[bb*3+1] += DOT4(h4, w4[1][kk]);
                    v[bb*3+2] += DOT4(h4, w4[2][kk]);
                }
            }
            // ---- reduce-scatter over the 32 c-lanes (bits 4,3,2 -> batch)
            #pragma unroll
            for (int i = 0; i < 12; ++i) {
                float send = (c & 16) ? v[i] : v[i+12];
                float keep = (c & 16) ? v[i+12] : v[i];
                v[i] = keep + __shfl_xor(send, 16);
            }
            #pragma unroll
            for (int i = 0; i < 6; ++i) {
                float send = (c & 8) ? v[i] : v[i+6];
                float keep = (c & 8) ? v[i+6] : v[i];
                v[i] = keep + __shfl_xor(send, 8);
            }
            #pragma unroll
            for (int i = 0; i < 3; ++i) {
                float send = (c & 4) ? v[i] : v[i+3];
                float keep = (c & 4) ? v[i+3] : v[i];
                v[i] = keep + __shfl_xor(send, 4);
            }
            #pragma unroll
            for (int i = 0; i < 3; ++i) v[i] += __shfl_xor(v[i], 2);
            #pragma unroll
            for (int i = 0; i < 3; ++i) v[i] += __shfl_xor(v[i], 1);
            ar = v[0]; az = v[1]; an = v[2];
        }

        float rg = 1.f / (1.f + expf(-(xr + ar + bhr)));
        float zg = 1.f / (1.f + expf(-(xz + az + bhz)));
        float ng = tanhf(xn + rg * (an + bhn));
        float hnew = (1.f - zg) * ng + zg * hold;
        hold = hnew;

        if (leader)
            __hip_atomic_store(states + (size_t)(batch*SEQT + t)*DIM + jg, hnew,
                               __ATOMIC_RELAXED, __HIP_MEMORY_SCOPE_AGENT);
        // drain bypass stores (completion = arrival at coherence point)
        asm volatile("s_waitcnt vmcnt(0)" ::: "memory");
        __syncthreads();
        if (tid == 0)
            __hip_atomic_fetch_add(cnt + (bg*SEQT + t)*16, 1,
                                   __ATOMIC_RELAXED, __HIP_MEMORY_SCOPE_AGENT);
    }
}

// =========================================================
// K3: probs[r] = sigmoid(dot(states[r], w_act) + b_act)
// =========================================================
__global__ __launch_bounds__(256, 4) void k_probs(
    const float* __restrict__ states, const float* __restrict__ w_act,
    const float* __restrict__ b_act, float* __restrict__ probs,
    float* __restrict__ out_probs)
{
    int row  = blockIdx.x*4 + (threadIdx.x >> 6);
    int lane = threadIdx.x & 63;
    const float* sr = states + (size_t)row * DIM;
    float s = 0.f;
    #pragma unroll
    for (int i = 0; i < 3; ++i) {
        float4 v = *(const float4*)(sr + i*256 + lane*4);
        float4 w = *(const float4*)(w_act + i*256 + lane*4);
        s += v.x*w.x + v.y*w.y + v.z*w.z + v.w*w.w;
    }
    #pragma unroll
    for (int off = 32; off > 0; off >>= 1) s += __shfl_xor(s, off);
    if (lane == 0) {
        float pv = 1.f / (1.f + expf(-(s + b_act[0])));
        probs[row]     = pv;
        out_probs[row] = pv;
    }
}

// =========================================================
// K4: per-batch halting scan -> weights, segment bounds, n_segs
// =========================================================
__global__ void k_scan(const float* __restrict__ probs, float* __restrict__ weights,
                       int* __restrict__ seg_start, int* __restrict__ seg_end,
                       int* __restrict__ n_segs)
{
    int b = threadIdx.x;
    if (b >= BATCH) return;
    float acc = 0.f;
    int s = 0, start = 0;
    for (int t0 = 0; t0 < SEQT; t0 += 4) {
        float4 p4 = *(const float4*)(probs + b*SEQT + t0);
        float pv[4] = {p4.x, p4.y, p4.z, p4.w};
        #pragma unroll
        for (int k = 0; k < 4; ++k) {
            int t = t0 + k;
            float pp = pv[k];
            acc += pp;
            float w = pp;
            if (acc > VTHRESH) {
                w = pp - (acc - 1.0f);
                seg_start[b*SEQT + s] = start;
                seg_end[b*SEQT + s]   = t;
                s++; start = t + 1; acc = 0.f;
            }
            weights[b*SEQT + t] = w;
        }
    }
    n_segs[b] = s;
}

// =========================================================
// K5: embs row (b,s) = sum_{t in segment s} weights[b,t]*states[b,t,:]
// =========================================================
__global__ __launch_bounds__(256, 4) void k_embs(
    const float* __restrict__ states, const float* __restrict__ weights,
    const int* __restrict__ seg_start, const int* __restrict__ seg_end,
    const int* __restrict__ n_segs, float* __restrict__ out)
{
    int r = blockIdx.x;
    int b = r / SEQT;
    int s = r - b*SEQT;
    int tid = threadIdx.x;
    float a0 = 0.f, a1 = 0.f, a2 = 0.f;
    if (s < n_segs[b]) {
        int st = seg_start[r], en = seg_end[r];
        for (int t = st; t <= en; ++t) {
            float w = weights[b*SEQT + t];
            const float* sp = states + (size_t)(b*SEQT + t) * DIM;
            a0 += w * sp[tid];
            a1 += w * sp[tid + 256];
            a2 += w * sp[tid + 512];
        }
    }
    float* o = out + (size_t)r * DIM;
    o[tid]       = a0;
    o[tid + 256] = a1;
    o[tid + 512] = a2;
}

__global__ void k_init(int* cnt) {
    cnt[blockIdx.x * 256 + threadIdx.x] = 0;
}

extern "C" void kernel_launch(void* const* d_in, const int* in_sizes, int n_in,
                              void* d_out, int out_size, void* d_ws, size_t ws_size,
                              hipStream_t stream)
{
    const int*   sent  = (const int*)d_in[0];
    const float* emb   = (const float*)d_in[1];
    const float* w_ih  = (const float*)d_in[2];
    const float* w_hh  = (const float*)d_in[3];
    const float* b_ih  = (const float*)d_in[4];
    const float* b_hh  = (const float*)d_in[5];
    const float* w_act = (const float*)d_in[6];
    const float* b_act = (const float*)d_in[7];
    float* out = (float*)d_out;

    char* ws = (char*)d_ws;
    float* xp      = (float*)(ws + OFF_XP);
    float* states  = (float*)(ws + OFF_ST);
    float* probs   = (float*)(ws + OFF_PR);
    float* weights = (float*)(ws + OFF_WT);
    int*   sstart  = (int*)(ws + OFF_SS);
    int*   send    = (int*)(ws + OFF_SE);
    int*   nsegs   = (int*)(ws + OFF_NS);
    int*   cnt     = (int*)(ws + OFF_CNT);

    k_init<<<NCNT/256, 256, 0, stream>>>(cnt);
    k_xp<<<dim3(96, 18), 256, 0, stream>>>(sent, emb, w_ih, b_ih, xp);
    k_gru<<<256, 384, 0, stream>>>(w_hh, b_hh, xp, states, cnt);
    k_probs<<<NROWS/4, 256, 0, stream>>>(states, w_act, b_act, probs,
                                         out + (size_t)NROWS * DIM);
    k_scan<<<1, 64, 0, stream>>>(probs, weights, sstart, send, nsegs);
    k_embs<<<NROWS, 256, 0, stream>>>(states, weights, sstart, send, nsegs, out);
}

// Round 5
// 3467.355 us; speedup vs baseline: 6.2626x; 1.3588x over previous
//
#include <hip/hip_runtime.h>
#include <math.h>

#define BATCH 32
#define SEQT 384
#define DIM 768
#define D3 2304
#define NROWS (BATCH*SEQT)      // 12288
#define VTHRESH 0.95f

typedef float  f32x4 __attribute__((ext_vector_type(4)));

// ---------------- workspace layout (bytes) ----------------
#define OFF_XP   ((size_t)0)
#define SZ_XP    ((size_t)NROWS * D3 * 4)            // 113,246,208
#define OFF_ST   (OFF_XP + SZ_XP)
#define SZ_ST    ((size_t)NROWS * DIM * 4)           // 37,748,736
#define OFF_PR   (OFF_ST + SZ_ST)
#define SZ_PR    ((size_t)NROWS * 4)
#define OFF_WT   (OFF_PR + SZ_PR)
#define OFF_SS   (OFF_WT + SZ_PR)
#define OFF_SE   (OFF_SS + SZ_PR)
#define OFF_NS   (OFF_SE + SZ_PR)
#define OFF_HB   (OFF_NS + 256)
// hbuf: 2 parity x 2 bg x 128 jb x 16 bl x 32B = 256 KiB
#define SZ_HB    ((size_t)262144)

#define DOT4(a,b) ((a).x*(b).x + (a).y*(b).y + (a).z*(b).z + (a).w*(b).w)

// =========================================================
// K1: xp[m][n] = sum_k emb[sent[m]][k] * w_ih[n][k] + b_ih[n]
// =========================================================
__global__ __launch_bounds__(256, 2) void k_xp(
    const int* __restrict__ sent, const float* __restrict__ emb,
    const float* __restrict__ w_ih, const float* __restrict__ b_ih,
    float* __restrict__ xp)
{
    __shared__ float As[16][132];
    __shared__ float Bs[16][132];
    const int tid = threadIdx.x;
    const int mt = blockIdx.x, nt = blockIdx.y;
    const int tx = tid & 15, ty = tid >> 4;
    const int lm = tid >> 2;          // 0..63
    const int lk = (tid & 3) << 2;    // 0,4,8,12

    const long arow0 = (long)sent[mt*128 + lm] * DIM;
    const long arow1 = (long)sent[mt*128 + lm + 64] * DIM;
    const float* b0p = w_ih + (size_t)(nt*128 + lm) * DIM;
    const float* b1p = w_ih + (size_t)(nt*128 + lm + 64) * DIM;

    float acc[8][8];
    #pragma unroll
    for (int i = 0; i < 8; ++i)
        #pragma unroll
        for (int j = 0; j < 8; ++j) acc[i][j] = 0.f;

    for (int k0 = 0; k0 < DIM; k0 += 16) {
        float4 a0 = *(const float4*)(emb + arow0 + k0 + lk);
        float4 a1 = *(const float4*)(emb + arow1 + k0 + lk);
        float4 b0 = *(const float4*)(b0p + k0 + lk);
        float4 b1 = *(const float4*)(b1p + k0 + lk);
        __syncthreads();
        As[lk+0][lm] = a0.x; As[lk+1][lm] = a0.y; As[lk+2][lm] = a0.z; As[lk+3][lm] = a0.w;
        As[lk+0][lm+64] = a1.x; As[lk+1][lm+64] = a1.y; As[lk+2][lm+64] = a1.z; As[lk+3][lm+64] = a1.w;
        Bs[lk+0][lm] = b0.x; Bs[lk+1][lm] = b0.y; Bs[lk+2][lm] = b0.z; Bs[lk+3][lm] = b0.w;
        Bs[lk+0][lm+64] = b1.x; Bs[lk+1][lm+64] = b1.y; Bs[lk+2][lm+64] = b1.z; Bs[lk+3][lm+64] = b1.w;
        __syncthreads();
        #pragma unroll
        for (int k = 0; k < 16; ++k) {
            float4 av0 = *(const float4*)&As[k][ty*8];
            float4 av1 = *(const float4*)&As[k][ty*8+4];
            float4 bv0 = *(const float4*)&Bs[k][tx*8];
            float4 bv1 = *(const float4*)&Bs[k][tx*8+4];
            float a[8] = {av0.x,av0.y,av0.z,av0.w,av1.x,av1.y,av1.z,av1.w};
            float b[8] = {bv0.x,bv0.y,bv0.z,bv0.w,bv1.x,bv1.y,bv1.z,bv1.w};
            #pragma unroll
            for (int i = 0; i < 8; ++i)
                #pragma unroll
                for (int j = 0; j < 8; ++j)
                    acc[i][j] += a[i]*b[j];
        }
    }

    const int m0 = mt*128 + ty*8;
    const int n0 = nt*128 + tx*8;
    float4 bi0 = *(const float4*)(b_ih + n0);
    float4 bi1 = *(const float4*)(b_ih + n0 + 4);
    #pragma unroll
    for (int i = 0; i < 8; ++i) {
        float4 v0, v1;
        v0.x = acc[i][0] + bi0.x; v0.y = acc[i][1] + bi0.y;
        v0.z = acc[i][2] + bi0.z; v0.w = acc[i][3] + bi0.w;
        v1.x = acc[i][4] + bi1.x; v1.y = acc[i][5] + bi1.y;
        v1.z = acc[i][6] + bi1.z; v1.w = acc[i][7] + bi1.w;
        *(float4*)(xp + (size_t)(m0+i)*D3 + n0)     = v0;
        *(float4*)(xp + (size_t)(m0+i)*D3 + n0 + 4) = v1;
    }
}

// =========================================================
// K2: persistent GRU recurrence, v4b — tag-validated data exchange.
//   (v4 failed to compile: HIP float4 is a struct, not a native vector,
//    so asm "v" constraints went indirect. Now ext_vector_type f32x4.)
//   - NO flags, NO atomics, NO fences: producers write packed 16B chunks
//     [h0,h1,h2,tag]/[h3,h4,h5,tag] (tag = raw int t+1 in .w) via
//     global_store_dwordx4 sc0 sc1 (16B aligned = single-copy atomic).
//     v3's 96 scattered 4B bypass stores/WG/step caused partial-sector
//     RMW at MALL (WRITE_SIZE 298MB = 8x states) — now 32x16B packed.
//   - Consumers poll the data chunks directly (coalesced dwordx4 sc0 sc1),
//     validate tags, drop into LDS. Deletes drain+flag+separate-load RTs.
//   - LDS k-space 8-strided (tag slots weight-0 in w4) so fill and
//     Phase B are both canonical stride-16B b128 ops.
//   - states[] stores are PLAIN cached (nobody reads them mid-kernel).
// =========================================================
#define HB_P 1032   // 1024 + 8 floats row pitch in LDS

__global__ __launch_bounds__(384, 1) void k_gru(
    const float* __restrict__ w_hh, const float* __restrict__ b_hh,
    const float* __restrict__ xp, float* __restrict__ states,
    char* __restrict__ hbuf)
{
    __shared__ float h_lds[16 * HB_P];    // 66,048 B
    __shared__ float out_lds[16 * 8];     // 512 B

    const int tid = threadIdx.x;
    const int jb  = blockIdx.x & 127;
    const int bg  = blockIdx.x >> 7;
    const int j    = tid >> 6;         // wave index 0..5
    const int lane = tid & 63;
    const int c    = lane & 31;
    const int bh   = lane >> 5;
    const int jg   = jb*6 + j;
    const int bloc  = (c >> 2) & 7;
    const int batch = bg*16 + bh*8 + bloc;
    const bool leader = ((c & 3) == 0);

    // w fragments in the 8-strided k16 space: position q = kk*128 + c*4
    // maps to source col (q>>3)*6 + ((q>>2)&1)*3 + i (i<3); slot 3 is the
    // tag position -> weight 0 (0 * small-int-as-float == 0).
    float4 w4[3][8];
    #pragma unroll
    for (int g3 = 0; g3 < 3; ++g3) {
        const float* wr = w_hh + (size_t)(g3*DIM + jg)*DIM;
        #pragma unroll
        for (int kk = 0; kk < 8; ++kk) {
            int q = kk*128 + c*4;
            int col = (q>>3)*6 + ((q>>2)&1)*3;
            w4[g3][kk] = make_float4(wr[col], wr[col+1], wr[col+2], 0.f);
        }
    }
    const float bhr = b_hh[jg];
    const float bhz = b_hh[DIM + jg];
    const float bhn = b_hh[2*DIM + jg];

    float hold = 0.f;

    for (int t = 0; t < SEQT; ++t) {
        // xp prefetch — independent of the exchange, issue first
        const float* xrow = xp + ((size_t)batch*SEQT + t)*D3 + jg;
        float xr = xrow[0], xz = xrow[DIM], xn = xrow[2*DIM];

        float ar = 0.f, az = 0.f, an = 0.f;
        if (t > 0) {
            // ---- poll step t-1 chunks (threads 0..255, 16 chunks each)
            if (tid < 256) {
                const char* pb = hbuf + ((((t-1)&1)*2 + bg) << 16);
                f32x4 ch[16];
                int need = 0xFFFF;
                while (need) {
                    #pragma unroll
                    for (int k = 0; k < 16; ++k)
                        if (need & (1<<k)) {
                            const f32x4* ap =
                                (const f32x4*)(pb + ((tid + (k<<8)) << 4));
                            asm volatile("global_load_dwordx4 %0, %1, off sc0 sc1"
                                         : "=v"(ch[k]) : "v"(ap));
                        }
                    asm volatile("s_waitcnt vmcnt(0)" ::: "memory");
                    #pragma unroll
                    for (int k = 0; k < 16; ++k)
                        if ((need & (1<<k)) && __float_as_int(ch[k].w) == t)
                            need &= ~(1<<k);
                    if (need) __builtin_amdgcn_s_sleep(1);
                }
                // chunk cid = jb*32 + bl*2 + half  ->  h_lds[bl][jb*8+half*4]
                #pragma unroll
                for (int k = 0; k < 16; ++k) {
                    int cid = tid + (k<<8);
                    *(f32x4*)&h_lds[((cid>>1)&15)*HB_P + (cid>>5)*8 + (cid&1)*4]
                        = ch[k];
                }
            }
            __syncthreads();

            // ---- Phase B: partial dots for 8 batches x 3 gates on slice c
            float v[24];
            #pragma unroll
            for (int i = 0; i < 24; ++i) v[i] = 0.f;
            const float* hb = h_lds + (bh*8)*HB_P + c*4;
            #pragma unroll
            for (int bb = 0; bb < 8; ++bb) {
                const float* hr = hb + bb*HB_P;
                #pragma unroll
                for (int kk = 0; kk < 8; ++kk) {
                    float4 h4 = *(const float4*)(hr + kk*128);
                    v[bb*3+0] += DOT4(h4, w4[0][kk]);
                    v[bb*3+1] += DOT4(h4, w4[1][kk]);
                    v[bb*3+2] += DOT4(h4, w4[2][kk]);
                }
            }
            // ---- reduce-scatter over the 32 c-lanes (bits 4,3,2 -> batch)
            #pragma unroll
            for (int i = 0; i < 12; ++i) {
                float send = (c & 16) ? v[i] : v[i+12];
                float keep = (c & 16) ? v[i+12] : v[i];
                v[i] = keep + __shfl_xor(send, 16);
            }
            #pragma unroll
            for (int i = 0; i < 6; ++i) {
                float send = (c & 8) ? v[i] : v[i+6];
                float keep = (c & 8) ? v[i+6] : v[i];
                v[i] = keep + __shfl_xor(send, 8);
            }
            #pragma unroll
            for (int i = 0; i < 3; ++i) {
                float send = (c & 4) ? v[i] : v[i+3];
                float keep = (c & 4) ? v[i+3] : v[i];
                v[i] = keep + __shfl_xor(send, 4);
            }
            #pragma unroll
            for (int i = 0; i < 3; ++i) v[i] += __shfl_xor(v[i], 2);
            #pragma unroll
            for (int i = 0; i < 3; ++i) v[i] += __shfl_xor(v[i], 1);
            ar = v[0]; az = v[1]; an = v[2];
        }

        float rg = 1.f / (1.f + expf(-(xr + ar + bhr)));
        float zg = 1.f / (1.f + expf(-(xz + az + bhz)));
        float ng = tanhf(xn + rg * (an + bhn));
        float hnew = (1.f - zg) * ng + zg * hold;
        hold = hnew;

        if (leader) {
            out_lds[(bh*8 + bloc)*8 + j] = hnew;
            states[(size_t)(batch*SEQT + t)*DIM + jg] = hnew;  // plain cached
        }
        __syncthreads();

        // ---- packed publish: wave 5 upper half, 32 lanes x 16B
        if (tid >= 352) {
            int lam = tid - 352;
            int bl = lam >> 1, hf = lam & 1;
            f32x4 val;
            val.x = out_lds[bl*8 + hf*3 + 0];
            val.y = out_lds[bl*8 + hf*3 + 1];
            val.z = out_lds[bl*8 + hf*3 + 2];
            val.w = __int_as_float(t + 1);
            f32x4* ap = (f32x4*)(hbuf + (((t&1)*2 + bg) << 16)
                                 + ((jb*16 + bl)*32 + hf*16));
            asm volatile("global_store_dwordx4 %0, %1, off sc0 sc1"
                         :: "v"(ap), "v"(val) : "memory");
        }
    }
}

// =========================================================
// K3: probs[r] = sigmoid(dot(states[r], w_act) + b_act)
// =========================================================
__global__ __launch_bounds__(256, 4) void k_probs(
    const float* __restrict__ states, const float* __restrict__ w_act,
    const float* __restrict__ b_act, float* __restrict__ probs,
    float* __restrict__ out_probs)
{
    int row  = blockIdx.x*4 + (threadIdx.x >> 6);
    int lane = threadIdx.x & 63;
    const float* sr = states + (size_t)row * DIM;
    float s = 0.f;
    #pragma unroll
    for (int i = 0; i < 3; ++i) {
        float4 v = *(const float4*)(sr + i*256 + lane*4);
        float4 w = *(const float4*)(w_act + i*256 + lane*4);
        s += v.x*w.x + v.y*w.y + v.z*w.z + v.w*w.w;
    }
    #pragma unroll
    for (int off = 32; off > 0; off >>= 1) s += __shfl_xor(s, off);
    if (lane == 0) {
        float pv = 1.f / (1.f + expf(-(s + b_act[0])));
        probs[row]     = pv;
        out_probs[row] = pv;
    }
}

// =========================================================
// K4: per-batch halting scan -> weights, segment bounds, n_segs
// =========================================================
__global__ void k_scan(const float* __restrict__ probs, float* __restrict__ weights,
                       int* __restrict__ seg_start, int* __restrict__ seg_end,
                       int* __restrict__ n_segs)
{
    int b = threadIdx.x;
    if (b >= BATCH) return;
    float acc = 0.f;
    int s = 0, start = 0;
    for (int t0 = 0; t0 < SEQT; t0 += 4) {
        float4 p4 = *(const float4*)(probs + b*SEQT + t0);
        float pv[4] = {p4.x, p4.y, p4.z, p4.w};
        #pragma unroll
        for (int k = 0; k < 4; ++k) {
            int t = t0 + k;
            float pp = pv[k];
            acc += pp;
            float w = pp;
            if (acc > VTHRESH) {
                w = pp - (acc - 1.0f);
                seg_start[b*SEQT + s] = start;
                seg_end[b*SEQT + s]   = t;
                s++; start = t + 1; acc = 0.f;
            }
            weights[b*SEQT + t] = w;
        }
    }
    n_segs[b] = s;
}

// =========================================================
// K5: embs row (b,s) = sum_{t in segment s} weights[b,t]*states[b,t,:]
// =========================================================
__global__ __launch_bounds__(256, 4) void k_embs(
    const float* __restrict__ states, const float* __restrict__ weights,
    const int* __restrict__ seg_start, const int* __restrict__ seg_end,
    const int* __restrict__ n_segs, float* __restrict__ out)
{
    int r = blockIdx.x;
    int b = r / SEQT;
    int s = r - b*SEQT;
    int tid = threadIdx.x;
    float a0 = 0.f, a1 = 0.f, a2 = 0.f;
    if (s < n_segs[b]) {
        int st = seg_start[r], en = seg_end[r];
        for (int t = st; t <= en; ++t) {
            float w = weights[b*SEQT + t];
            const float* sp = states + (size_t)(b*SEQT + t) * DIM;
            a0 += w * sp[tid];
            a1 += w * sp[tid + 256];
            a2 += w * sp[tid + 512];
        }
    }
    float* o = out + (size_t)r * DIM;
    o[tid]       = a0;
    o[tid + 256] = a1;
    o[tid + 512] = a2;
}

__global__ void k_init(float* hb) {
    hb[blockIdx.x * 256 + threadIdx.x] = 0.f;   // 65536 floats = 256KB
}

extern "C" void kernel_launch(void* const* d_in, const int* in_sizes, int n_in,
                              void* d_out, int out_size, void* d_ws, size_t ws_size,
                              hipStream_t stream)
{
    const int*   sent  = (const int*)d_in[0];
    const float* emb   = (const float*)d_in[1];
    const float* w_ih  = (const float*)d_in[2];
    const float* w_hh  = (const float*)d_in[3];
    const float* b_ih  = (const float*)d_in[4];
    const float* b_hh  = (const float*)d_in[5];
    const float* w_act = (const float*)d_in[6];
    const float* b_act = (const float*)d_in[7];
    float* out = (float*)d_out;

    char* ws = (char*)d_ws;
    float* xp      = (float*)(ws + OFF_XP);
    float* states  = (float*)(ws + OFF_ST);
    float* probs   = (float*)(ws + OFF_PR);
    float* weights = (float*)(ws + OFF_WT);
    int*   sstart  = (int*)(ws + OFF_SS);
    int*   send    = (int*)(ws + OFF_SE);
    int*   nsegs   = (int*)(ws + OFF_NS);
    char*  hbuf    = (char*)(ws + OFF_HB);

    k_init<<<256, 256, 0, stream>>>((float*)hbuf);
    k_xp<<<dim3(96, 18), 256, 0, stream>>>(sent, emb, w_ih, b_ih, xp);
    k_gru<<<256, 384, 0, stream>>>(w_hh, b_hh, xp, states, hbuf);
    k_probs<<<NROWS/4, 256, 0, stream>>>(states, w_act, b_act, probs,
                                         out + (size_t)NROWS * DIM);
    k_scan<<<1, 64, 0, stream>>>(probs, weights, sstart, send, nsegs);
    k_embs<<<NROWS, 256, 0, stream>>>(states, weights, sstart, send, nsegs, out);
}